// Round 1
// baseline (7638.931 us; speedup 1.0000x reference)
//
#include <hip/hip_runtime.h>
#include <hip/hip_bf16.h>
#include <hip/hip_fp16.h>

// ---------------------------------------------------------------------------
// 3-layer GRU (Keras v2, reset_after=True), B=64 T=2048 F=H=128, OUT=5.
// Design (round 0):
//   per layer: in_proj  (xw = X @ K + b_in, parallel over B*T rows, f16 out)
//              gru_rec  (sequential over T; 1 workgroup per batch; recurrent
//                        weights persistent in VGPRs as packed f16; h state in
//                        LDS as f16; fp32 gate math)
//   then     : out_proj (h @ wo + bo)
// Workspace: xw f16 [B*T,384] = 100.7MB at offset 0; h fp32 [B*T,128] = 67.1MB
// after it. Total 160 MB.
// Precision: all storage rounding in f16 (rel ~2^-11), math fp32 -> predicted
// absmax ~1e-3 vs threshold 2.44e-2.
// ---------------------------------------------------------------------------

#define HID   128
#define H3    384
#define T_SEQ 2048

typedef _Float16 f16x2 __attribute__((ext_vector_type(2)));
typedef _Float16 f16x8 __attribute__((ext_vector_type(8)));

__device__ __forceinline__ float fdot2(f16x2 a, f16x2 b, float c) {
#if __has_builtin(__builtin_amdgcn_fdot2)
    return __builtin_amdgcn_fdot2(a, b, c, false);   // v_dot2_f32_f16
#else
    return fmaf((float)a.x, (float)b.x, fmaf((float)a.y, (float)b.y, c));
#endif
}

__device__ __forceinline__ float fexp2(float x) {
#if __has_builtin(__builtin_amdgcn_exp2f)
    return __builtin_amdgcn_exp2f(x);
#else
    return exp2f(x);
#endif
}

__device__ __forceinline__ float frcp(float x) {
#if __has_builtin(__builtin_amdgcn_rcpf)
    return __builtin_amdgcn_rcpf(x);
#else
    return 1.f / x;
#endif
}

__device__ __forceinline__ float fsigmoid(float x) {
    x = fminf(fmaxf(x, -30.f), 30.f);
    const float e = fexp2(x * -1.4426950408889634f);   // exp(-x)
    return frcp(1.f + e);
}

__device__ __forceinline__ float ftanh_(float x) {
    x = fminf(fmaxf(x, -15.f), 15.f);
    const float e = fexp2(x * -2.8853900817779268f);   // exp(-2x)
    return (1.f - e) * frcp(1.f + e);
}

// ---------------------------------------------------------------------------
// in_proj: XW[r, :] = X[r, :] @ Kw + bias_in   (f16 output)
// lane = row; weights are lane-uniform -> scalar loads; X tile staged in LDS.
// 128 threads / block, 128 rows / block. JB=32 column block (12 passes) so the
// LDS row re-read cost (32KB/wave/pass) stays ~4x under the FMA cost.
// ---------------------------------------------------------------------------
#define PADW 132   // row stride in floats: 132*4=528B, 16B aligned for float4

__global__ __launch_bounds__(128) void in_proj(
    const float* __restrict__ X,     // [R,128]
    const float* __restrict__ Kw,    // [128,384]
    const float* __restrict__ bias,  // [2,384], row 0 = input bias
    _Float16*   __restrict__ XW,     // [R,384]
    int R)
{
    __shared__ float xs[128 * PADW];
    const int t  = threadIdx.x;
    const int r0 = blockIdx.x * 128;

    for (int rr = 0; rr < 128; ++rr) {
        const int row = r0 + rr;
        xs[rr * PADW + t] = (row < R) ? X[(size_t)row * HID + t] : 0.f;
    }
    __syncthreads();

    const int myrow = r0 + t;
    if (myrow >= R) return;

    const float* xrow = xs + t * PADW;
    for (int jb = 0; jb < H3 / 32; ++jb) {
        const int j0 = jb * 32;
        float acc[32];
#pragma unroll
        for (int o = 0; o < 32; ++o) acc[o] = bias[j0 + o];

        for (int k = 0; k < HID; k += 4) {
            const float4 xv = *(const float4*)(xrow + k);
            const float* kw0 = Kw + (size_t)(k + 0) * H3 + j0;
            const float* kw1 = Kw + (size_t)(k + 1) * H3 + j0;
            const float* kw2 = Kw + (size_t)(k + 2) * H3 + j0;
            const float* kw3 = Kw + (size_t)(k + 3) * H3 + j0;
#pragma unroll
            for (int o = 0; o < 32; ++o) {
                acc[o] = fmaf(xv.x, kw0[o], acc[o]);
                acc[o] = fmaf(xv.y, kw1[o], acc[o]);
                acc[o] = fmaf(xv.z, kw2[o], acc[o]);
                acc[o] = fmaf(xv.w, kw3[o], acc[o]);
            }
        }

        f16x8 pk[4];
#pragma unroll
        for (int g = 0; g < 4; ++g)
#pragma unroll
            for (int o = 0; o < 8; ++o) pk[g][o] = (_Float16)acc[g * 8 + o];
        f16x8* dst = (f16x8*)(XW + (size_t)myrow * H3 + j0);
#pragma unroll
        for (int g = 0; g < 4; ++g) dst[g] = pk[g];
    }
}

// ---------------------------------------------------------------------------
// gru_rec: one workgroup per batch. 768 threads: thread = (col 0..383, khalf).
// Each thread holds its half-column of rk as 32 packed f16 pairs in VGPRs.
// Per step: dot (v_dot2 over LDS-broadcast f16 h) -> shfl pair-reduce ->
// ri to LDS -> barrier -> gates on threads 0..127 (fp32, xw prefetched 2 steps
// ahead from global f16) -> new h to LDS(f16) + global(fp32) -> barrier.
// ---------------------------------------------------------------------------
__global__ __launch_bounds__(768) void gru_rec(
    const _Float16* __restrict__ xw,   // [B*T, 384]  z|r|h blocks of 128
    const float*    __restrict__ rk,   // [128, 384]
    const float*    __restrict__ bias, // [2, 384], row 1 = recurrent bias
    float*          __restrict__ h_out,// [B*T, 128]
    int T)
{
    const int b   = blockIdx.x;
    const int t   = threadIdx.x;
    const int col = t >> 1;
    const int kh  = t & 1;

    __shared__ __align__(16) _Float16 h_state[HID];
    __shared__ float ri_sh[H3];

    f16x2 w2[32];
#pragma unroll
    for (int p = 0; p < 32; ++p) {
        const int krow = kh * 64 + 2 * p;
        f16x2 wv;
        wv.x = (_Float16)rk[(size_t)krow * H3 + col];
        wv.y = (_Float16)rk[(size_t)(krow + 1) * H3 + col];
        w2[p] = wv;
    }
    const float brec = bias[H3 + col];

    if (t < HID) h_state[t] = (_Float16)0.f;

    const _Float16* xwb = xw + (size_t)b * T * H3;
    float*          hob = h_out + (size_t)b * T * HID;

    // xw register double-buffer, 2 steps of lookahead
    float cz = 0.f, cr = 0.f, ch = 0.f, nz = 0.f, nr = 0.f, nh = 0.f;
    if (t < HID) {
        cz = (float)xwb[t];
        cr = (float)xwb[HID + t];
        ch = (float)xwb[2 * HID + t];
        if (T > 1) {
            const _Float16* p1 = xwb + H3;
            nz = (float)p1[t]; nr = (float)p1[HID + t]; nh = (float)p1[2 * HID + t];
        }
    }
    __syncthreads();

    const f16x8* hp = (const f16x8*)h_state + kh * 8;

    for (int step = 0; step < T; ++step) {
        // ---- dot: ri[col] partial over this thread's k-half ----
        float a0 = 0.f, a1 = 0.f, a2 = 0.f, a3 = 0.f;
#pragma unroll
        for (int i = 0; i < 8; ++i) {
            union { f16x8 v; f16x2 p[4]; } u;
            u.v = hp[i];
            a0 = fdot2(u.p[0], w2[4 * i + 0], a0);
            a1 = fdot2(u.p[1], w2[4 * i + 1], a1);
            a2 = fdot2(u.p[2], w2[4 * i + 2], a2);
            a3 = fdot2(u.p[3], w2[4 * i + 3], a3);
        }
        float part = (a0 + a1) + (a2 + a3);
        part += __shfl_xor(part, 1);
        if (kh == 0) ri_sh[col] = part + brec;
        __syncthreads();

        // ---- gates on threads 0..127 ----
        if (t < HID) {
            const float uz = cz, ur = cr, uh = ch;
            cz = nz; cr = nr; ch = nh;
            if (step + 2 < T) {            // issue next loads early
                const _Float16* p2 = xwb + (size_t)(step + 2) * H3;
                nz = (float)p2[t]; nr = (float)p2[HID + t]; nh = (float)p2[2 * HID + t];
            }
            const float z  = fsigmoid(uz + ri_sh[t]);
            const float r  = fsigmoid(ur + ri_sh[HID + t]);
            const float hh = ftanh_(uh + r * ri_sh[2 * HID + t]);
            const float hn = z * (float)h_state[t] + (1.f - z) * hh;
            h_state[t] = (_Float16)hn;
            hob[(size_t)step * HID + t] = hn;
        }
        __syncthreads();
    }
}

// ---------------------------------------------------------------------------
// out_proj: out[r, :] = H[r, :] @ wo + bo. lane = row, wo lane-uniform.
// ---------------------------------------------------------------------------
__global__ __launch_bounds__(128) void out_proj(
    const float* __restrict__ Hf,   // [R,128]
    const float* __restrict__ wo,   // [128,5]
    const float* __restrict__ bo,   // [5]
    float*       __restrict__ out,  // [R,5]
    int R)
{
    __shared__ float xs[128 * (HID + 1)];
    const int t  = threadIdx.x;
    const int r0 = blockIdx.x * 128;

    for (int rr = 0; rr < 128; ++rr) {
        const int row = r0 + rr;
        xs[rr * (HID + 1) + t] = (row < R) ? Hf[(size_t)row * HID + t] : 0.f;
    }
    __syncthreads();

    const int myrow = r0 + t;
    if (myrow >= R) return;

    float a0 = bo[0], a1 = bo[1], a2 = bo[2], a3 = bo[3], a4 = bo[4];
    const float* xrow = xs + t * (HID + 1);
    for (int k = 0; k < HID; ++k) {
        const float xv = xrow[k];
        const float* w = wo + k * 5;
        a0 = fmaf(xv, w[0], a0);
        a1 = fmaf(xv, w[1], a1);
        a2 = fmaf(xv, w[2], a2);
        a3 = fmaf(xv, w[3], a3);
        a4 = fmaf(xv, w[4], a4);
    }
    float* op = out + (size_t)myrow * 5;
    op[0] = a0; op[1] = a1; op[2] = a2; op[3] = a3; op[4] = a4;
}

// ---------------------------------------------------------------------------
extern "C" void kernel_launch(void* const* d_in, const int* in_sizes, int n_in,
                              void* d_out, int out_size, void* d_ws, size_t ws_size,
                              hipStream_t stream) {
    const float* x   = (const float*)d_in[0];
    const float* k0  = (const float*)d_in[1];
    const float* rk0 = (const float*)d_in[2];
    const float* b0  = (const float*)d_in[3];
    const float* k1  = (const float*)d_in[4];
    const float* rk1 = (const float*)d_in[5];
    const float* b1  = (const float*)d_in[6];
    const float* k2  = (const float*)d_in[7];
    const float* rk2 = (const float*)d_in[8];
    const float* b2  = (const float*)d_in[9];
    const float* wo  = (const float*)d_in[10];
    const float* bo  = (const float*)d_in[11];
    float* out = (float*)d_out;

    const int BT = in_sizes[0] / HID;   // 64*2048 = 131072 rows
    const int T  = T_SEQ;               // 2048
    const int B  = BT / T;              // 64

    // workspace: [xw f16 BT*384][h fp32 BT*128]
    _Float16* xwbuf = (_Float16*)d_ws;
    float*    hbuf  = (float*)((char*)d_ws + (size_t)BT * H3 * sizeof(_Float16));

    const int pg = (BT + 127) / 128;

    in_proj <<<pg, 128, 0, stream>>>(x,    k0, b0, xwbuf, BT);
    gru_rec <<<B, 768, 0, stream>>>(xwbuf, rk0, b0, hbuf, T);
    in_proj <<<pg, 128, 0, stream>>>(hbuf, k1, b1, xwbuf, BT);
    gru_rec <<<B, 768, 0, stream>>>(xwbuf, rk1, b1, hbuf, T);
    in_proj <<<pg, 128, 0, stream>>>(hbuf, k2, b2, xwbuf, BT);
    gru_rec <<<B, 768, 0, stream>>>(xwbuf, rk2, b2, hbuf, T);
    out_proj<<<pg, 128, 0, stream>>>(hbuf, wo, bo, out, BT);
}

// Round 2
// 5804.230 us; speedup vs baseline: 1.3161x; 1.3161x over previous
//
#include <hip/hip_runtime.h>
#include <hip/hip_bf16.h>
#include <hip/hip_fp16.h>

// ---------------------------------------------------------------------------
// 3-layer GRU (Keras v2, reset_after=True), B=64 T=2048 F=H=128, OUT=5.
// Round 2:
//   gru_rec v2: 256 thr (4 waves). Thread owns the full gate triple for one
//     hidden unit j (cols j, j+128, j+256) over one k-half; lane^1 shfl_xor
//     reduce; gates computed redundantly in both k-half lanes; h_old in
//     register; double-buffered f16 h in LDS -> ONE barrier/step.
//     LDS b128/step: 96 -> 32. Predicted ~550 cy/step -> ~480 us/layer.
//   in_proj v2: no LDS; x row re-read per 32-col pass as float4 (L1/L2);
//     weights via lane-uniform loads; 2 blocks/CU for latency hiding.
//   out_proj v2: register-only, same style.
// Workspace: xw f16 [B*T,384] = 100.7MB; h fp32 [B*T,128] = 67.1MB.
// ---------------------------------------------------------------------------

#define HID   128
#define H3    384
#define OUTD  5
#define T_SEQ 2048

typedef _Float16 f16x2 __attribute__((ext_vector_type(2)));
typedef _Float16 f16x8 __attribute__((ext_vector_type(8)));

__device__ __forceinline__ float fdot2(f16x2 a, f16x2 b, float c) {
#if __has_builtin(__builtin_amdgcn_fdot2)
    return __builtin_amdgcn_fdot2(a, b, c, false);   // v_dot2_f32_f16
#else
    return fmaf((float)a.x, (float)b.x, fmaf((float)a.y, (float)b.y, c));
#endif
}

__device__ __forceinline__ float fexp2(float x) {
#if __has_builtin(__builtin_amdgcn_exp2f)
    return __builtin_amdgcn_exp2f(x);
#else
    return exp2f(x);
#endif
}

__device__ __forceinline__ float frcp(float x) {
#if __has_builtin(__builtin_amdgcn_rcpf)
    return __builtin_amdgcn_rcpf(x);
#else
    return 1.f / x;
#endif
}

__device__ __forceinline__ float fsigmoid(float x) {
    x = fminf(fmaxf(x, -30.f), 30.f);
    const float e = fexp2(x * -1.4426950408889634f);   // exp(-x)
    return frcp(1.f + e);
}

__device__ __forceinline__ float ftanh_(float x) {
    x = fminf(fmaxf(x, -15.f), 15.f);
    const float e = fexp2(x * -2.8853900817779268f);   // exp(-2x)
    return (1.f - e) * frcp(1.f + e);
}

// ---------------------------------------------------------------------------
// in_proj: XW[r,:] = X[r,:] @ Kw + bias_in   (f16 out). Thread = row.
// x read as float4 from global per 32-col pass (L1/L2 cached); weights are
// lane-uniform -> scalar loads. 256 thr/block, 2 blocks/CU.
// ---------------------------------------------------------------------------
__global__ __launch_bounds__(256, 2) void in_proj(
    const float* __restrict__ X,     // [R,128]
    const float* __restrict__ Kw,    // [128,384]
    const float* __restrict__ bias,  // [2,384], row 0 = input bias
    _Float16*   __restrict__ XW,     // [R,384]
    int R)
{
    const int r = blockIdx.x * 256 + threadIdx.x;
    if (r >= R) return;
    const float4* xp = (const float4*)(X + (size_t)r * HID);
    _Float16* orow = XW + (size_t)r * H3;

#pragma unroll 1
    for (int jb = 0; jb < H3 / 32; ++jb) {
        const int j0 = jb * 32;
        float acc[32];
#pragma unroll
        for (int o = 0; o < 32; ++o) acc[o] = bias[j0 + o];

#pragma unroll 2
        for (int k4 = 0; k4 < HID / 4; ++k4) {
            const float4 xv = xp[k4];
            const float* w0 = Kw + (size_t)(4 * k4 + 0) * H3 + j0;
            const float* w1 = Kw + (size_t)(4 * k4 + 1) * H3 + j0;
            const float* w2 = Kw + (size_t)(4 * k4 + 2) * H3 + j0;
            const float* w3 = Kw + (size_t)(4 * k4 + 3) * H3 + j0;
#pragma unroll
            for (int o = 0; o < 32; ++o) {
                acc[o] = fmaf(xv.x, w0[o], acc[o]);
                acc[o] = fmaf(xv.y, w1[o], acc[o]);
                acc[o] = fmaf(xv.z, w2[o], acc[o]);
                acc[o] = fmaf(xv.w, w3[o], acc[o]);
            }
        }

        f16x8 pk[4];
#pragma unroll
        for (int g = 0; g < 4; ++g)
#pragma unroll
            for (int o2 = 0; o2 < 8; ++o2) pk[g][o2] = (_Float16)acc[g * 8 + o2];
        f16x8* dst = (f16x8*)(orow + j0);
#pragma unroll
        for (int g = 0; g < 4; ++g) dst[g] = pk[g];
    }
}

// ---------------------------------------------------------------------------
// gru_rec v2: one WG (256 thr, 4 waves) per batch.
// lane l of wave w: jl=l>>1, kh=l&1, j=w*32+jl. Thread computes partial dots
// (k in [64kh,64kh+64)) for cols j / j+128 / j+256, shfl_xor(1) to reduce,
// then full gate math redundantly in both kh lanes. h f16 double-buffer in
// LDS; one barrier per step.
// ---------------------------------------------------------------------------
__global__ __launch_bounds__(256, 1) void gru_rec(
    const _Float16* __restrict__ xw,   // [B*T, 384]  z|r|h blocks of 128
    const float*    __restrict__ rk,   // [128, 384]
    const float*    __restrict__ bias, // [2, 384], row 1 = recurrent bias
    float*          __restrict__ h_out,// [B*T, 128]
    int T)
{
    const int b  = blockIdx.x;
    const int t  = threadIdx.x;
    const int w  = t >> 6;
    const int l  = t & 63;
    const int jl = l >> 1;
    const int kh = l & 1;
    const int j  = w * 32 + jl;     // hidden unit 0..127
    const int k0 = kh * 64;         // k-half base

    __shared__ __align__(16) _Float16 hbuf[2][HID];

    // persistent weights: 3 cols x 32 f16x2 pairs = 96 VGPRs
    f16x2 wz[32], wr[32], wh[32];
#pragma unroll
    for (int p = 0; p < 32; ++p) {
        const int k = k0 + 2 * p;
        const float* r0p = rk + (size_t)k * H3;
        const float* r1p = rk + (size_t)(k + 1) * H3;
        f16x2 a;
        a.x = (_Float16)r0p[j];       a.y = (_Float16)r1p[j];       wz[p] = a;
        a.x = (_Float16)r0p[j + 128]; a.y = (_Float16)r1p[j + 128]; wr[p] = a;
        a.x = (_Float16)r0p[j + 256]; a.y = (_Float16)r1p[j + 256]; wh[p] = a;
    }
    const float bz = bias[H3 + j];
    const float br = bias[H3 + 128 + j];
    const float bh = bias[H3 + 256 + j];

    if (t < HID) { hbuf[0][t] = (_Float16)0.f; hbuf[1][t] = (_Float16)0.f; }

    const _Float16* xwb = xw + (size_t)b * T * H3;
    float*          hob = h_out + (size_t)b * T * HID;

    // xw prefetch, 2 steps of lookahead
    float cz = (float)xwb[j], cr = (float)xwb[128 + j], ch = (float)xwb[256 + j];
    float nz, nr, nh;
    {
        const _Float16* p1 = xwb + H3;
        nz = (float)p1[j]; nr = (float)p1[128 + j]; nh = (float)p1[256 + j];
    }

    float h_old = 0.f;
    __syncthreads();

    int buf = 0;
    for (int step = 0; step < T; ++step) {
        const f16x8* hp = (const f16x8*)(&hbuf[buf][k0]);
        float az = 0.f, ar = 0.f, ah = 0.f;
#pragma unroll
        for (int i = 0; i < 8; ++i) {
            union { f16x8 v; f16x2 p[4]; } u;
            u.v = hp[i];
#pragma unroll
            for (int q = 0; q < 4; ++q) {
                az = fdot2(u.p[q], wz[4 * i + q], az);
                ar = fdot2(u.p[q], wr[4 * i + q], ar);
                ah = fdot2(u.p[q], wh[4 * i + q], ah);
            }
        }
        az += __shfl_xor(az, 1);
        ar += __shfl_xor(ar, 1);
        ah += __shfl_xor(ah, 1);

        const float xz = cz, xr = cr, xh = ch;
        cz = nz; cr = nr; ch = nh;
        if (step + 2 < T) {
            const _Float16* p2 = xwb + (size_t)(step + 2) * H3;
            nz = (float)p2[j]; nr = (float)p2[128 + j]; nh = (float)p2[256 + j];
        }

        const float z  = fsigmoid(xz + az + bz);
        const float r  = fsigmoid(xr + ar + br);
        const float hh = ftanh_(xh + (ah + bh) * r);
        const float hn = z * h_old + (1.f - z) * hh;
        h_old = hn;

        if (kh == 0) {
            hbuf[buf ^ 1][j] = (_Float16)hn;
            hob[(size_t)step * HID + j] = hn;
        }
        buf ^= 1;
        __syncthreads();
    }
}

// ---------------------------------------------------------------------------
// out_proj: out[r,:] = H[r,:] @ wo + bo. Thread = row, register-only.
// ---------------------------------------------------------------------------
__global__ __launch_bounds__(256) void out_proj(
    const float* __restrict__ Hf,   // [R,128]
    const float* __restrict__ wo,   // [128,5]
    const float* __restrict__ bo,   // [5]
    float*       __restrict__ out,  // [R,5]
    int R)
{
    const int r = blockIdx.x * 256 + threadIdx.x;
    if (r >= R) return;
    const float4* xp = (const float4*)(Hf + (size_t)r * HID);

    float a0 = bo[0], a1 = bo[1], a2 = bo[2], a3 = bo[3], a4 = bo[4];
#pragma unroll 4
    for (int k4 = 0; k4 < HID / 4; ++k4) {
        const float4 xv = xp[k4];
        const float* wp = wo + (size_t)(4 * k4) * OUTD;
        a0 = fmaf(xv.x, wp[0], a0);  a1 = fmaf(xv.x, wp[1], a1);
        a2 = fmaf(xv.x, wp[2], a2);  a3 = fmaf(xv.x, wp[3], a3);
        a4 = fmaf(xv.x, wp[4], a4);
        a0 = fmaf(xv.y, wp[5], a0);  a1 = fmaf(xv.y, wp[6], a1);
        a2 = fmaf(xv.y, wp[7], a2);  a3 = fmaf(xv.y, wp[8], a3);
        a4 = fmaf(xv.y, wp[9], a4);
        a0 = fmaf(xv.z, wp[10], a0); a1 = fmaf(xv.z, wp[11], a1);
        a2 = fmaf(xv.z, wp[12], a2); a3 = fmaf(xv.z, wp[13], a3);
        a4 = fmaf(xv.z, wp[14], a4);
        a0 = fmaf(xv.w, wp[15], a0); a1 = fmaf(xv.w, wp[16], a1);
        a2 = fmaf(xv.w, wp[17], a2); a3 = fmaf(xv.w, wp[18], a3);
        a4 = fmaf(xv.w, wp[19], a4);
    }
    float* op = out + (size_t)r * OUTD;
    op[0] = a0; op[1] = a1; op[2] = a2; op[3] = a3; op[4] = a4;
}

// ---------------------------------------------------------------------------
extern "C" void kernel_launch(void* const* d_in, const int* in_sizes, int n_in,
                              void* d_out, int out_size, void* d_ws, size_t ws_size,
                              hipStream_t stream) {
    const float* x   = (const float*)d_in[0];
    const float* k0  = (const float*)d_in[1];
    const float* rk0 = (const float*)d_in[2];
    const float* b0  = (const float*)d_in[3];
    const float* k1  = (const float*)d_in[4];
    const float* rk1 = (const float*)d_in[5];
    const float* b1  = (const float*)d_in[6];
    const float* k2  = (const float*)d_in[7];
    const float* rk2 = (const float*)d_in[8];
    const float* b2  = (const float*)d_in[9];
    const float* wo  = (const float*)d_in[10];
    const float* bo  = (const float*)d_in[11];
    float* out = (float*)d_out;

    const int BT = in_sizes[0] / HID;   // 64*2048 = 131072 rows
    const int T  = T_SEQ;               // 2048
    const int B  = BT / T;              // 64

    _Float16* xwbuf = (_Float16*)d_ws;
    float*    hbuf  = (float*)((char*)d_ws + (size_t)BT * H3 * sizeof(_Float16));

    const int pg = (BT + 255) / 256;

    in_proj <<<pg, 256, 0, stream>>>(x,    k0, b0, xwbuf, BT);
    gru_rec <<<B, 256, 0, stream>>>(xwbuf, rk0, b0, hbuf, T);
    in_proj <<<pg, 256, 0, stream>>>(hbuf, k1, b1, xwbuf, BT);
    gru_rec <<<B, 256, 0, stream>>>(xwbuf, rk1, b1, hbuf, T);
    in_proj <<<pg, 256, 0, stream>>>(hbuf, k2, b2, xwbuf, BT);
    gru_rec <<<B, 256, 0, stream>>>(xwbuf, rk2, b2, hbuf, T);
    out_proj<<<pg, 256, 0, stream>>>(hbuf, wo, bo, out, BT);
}

// Round 3
// 3855.044 us; speedup vs baseline: 1.9815x; 1.5056x over previous
//
#include <hip/hip_runtime.h>
#include <hip/hip_bf16.h>
#include <hip/hip_fp16.h>

// ---------------------------------------------------------------------------
// 3-layer GRU (Keras v2, reset_after=True), B=64 T=2048 F=H=128, OUT=5.
// Round 3:
//   gru_rec v3: 512 thr (8 waves, 2/SIMD). thread=(unit j, kh 0..3); 16-deep
//     dot2 chains; quad butterfly reduce via DPP (VALU, not LDS); xw prefetch
//     ring depth 4 with manual x4 unroll (slack ~2000cy > 900cy HBM lat);
//     h f16 double-buffer in LDS, ONE barrier/step.
//   in_proj v3: weights repacked to f16x2 by pack_w; x row resident as f16x2;
//     inner loop 4 float4 weight loads per 16 dot2 (VALU-bound ~60us).
//   h stored f16 between layers (ws: xw 100.6MB + h 33.5MB + wpk 0.1MB).
// ---------------------------------------------------------------------------

#define HID   128
#define H3    384
#define OUTD  5
#define T_SEQ 2048

typedef _Float16 f16x2 __attribute__((ext_vector_type(2)));
typedef _Float16 f16x4 __attribute__((ext_vector_type(4)));
typedef _Float16 f16x8 __attribute__((ext_vector_type(8)));

__device__ __forceinline__ float fdot2(f16x2 a, f16x2 b, float c) {
#if __has_builtin(__builtin_amdgcn_fdot2)
    return __builtin_amdgcn_fdot2(a, b, c, false);   // v_dot2_f32_f16
#else
    return fmaf((float)a.x, (float)b.x, fmaf((float)a.y, (float)b.y, c));
#endif
}

__device__ __forceinline__ float fexp2(float x) {
#if __has_builtin(__builtin_amdgcn_exp2f)
    return __builtin_amdgcn_exp2f(x);
#else
    return exp2f(x);
#endif
}

__device__ __forceinline__ float frcp(float x) {
#if __has_builtin(__builtin_amdgcn_rcpf)
    return __builtin_amdgcn_rcpf(x);
#else
    return 1.f / x;
#endif
}

__device__ __forceinline__ float fsigmoid(float x) {
    x = fminf(fmaxf(x, -30.f), 30.f);
    const float e = fexp2(x * -1.4426950408889634f);   // exp(-x)
    return frcp(1.f + e);
}

__device__ __forceinline__ float ftanh_(float x) {
    x = fminf(fmaxf(x, -15.f), 15.f);
    const float e = fexp2(x * -2.8853900817779268f);   // exp(-2x)
    return (1.f - e) * frcp(1.f + e);
}

// butterfly sum over the kh quad (lanes xor 1, xor 2) on the VALU pipe
__device__ __forceinline__ float quad_sum(float x) {
#if __has_builtin(__builtin_amdgcn_mov_dpp)
    int i1 = __builtin_amdgcn_mov_dpp(__float_as_int(x), 0xB1, 0xF, 0xF, true); // quad_perm [1,0,3,2]
    x += __int_as_float(i1);
    int i2 = __builtin_amdgcn_mov_dpp(__float_as_int(x), 0x4E, 0xF, 0xF, true); // quad_perm [2,3,0,1]
    x += __int_as_float(i2);
#else
    x += __shfl_xor(x, 1);
    x += __shfl_xor(x, 2);
#endif
    return x;
}

// ---------------------------------------------------------------------------
// pack_w: Kw fp32 [128,384] -> wpk[g][k2][u] f16x2 = (Kw[2k2][g*128+u], Kw[2k2+1][g*128+u])
// ---------------------------------------------------------------------------
__global__ __launch_bounds__(256) void pack_w(const float* __restrict__ Kw,
                                              f16x2* __restrict__ wpk) {
    const int i = blockIdx.x * 256 + threadIdx.x;
    if (i >= 3 * 64 * 128) return;
    const int u  = i & 127;
    const int k2 = (i >> 7) & 63;
    const int g  = i >> 13;
    f16x2 v;
    v.x = (_Float16)Kw[(size_t)(2 * k2) * H3 + g * 128 + u];
    v.y = (_Float16)Kw[(size_t)(2 * k2 + 1) * H3 + g * 128 + u];
    wpk[i] = v;
}

// ---------------------------------------------------------------------------
// in_proj v3: XW[r,:] = x_f16[r,:] @ W + b_in, f16 out in z|r|h plane layout.
// Thread = row. x row resident as 64 f16x2; weights from wpk as float4 loads.
// 8 unit-blocks of 16; per k2: 12 float4 loads + 48 dot2.
// ---------------------------------------------------------------------------
template<bool F32IN>
__global__ __launch_bounds__(256, 2) void in_proj(
    const void* __restrict__ Xv,     // [R,128] fp32 or f16
    const f16x2* __restrict__ wpk,   // [3][64][128]
    const float* __restrict__ bias,  // [2,384], row 0 = input bias
    _Float16*   __restrict__ XW,     // [R,384] planes z|r|h
    int R)
{
    const int r = blockIdx.x * 256 + threadIdx.x;
    if (r >= R) return;

    f16x2 xr[64];
    if (F32IN) {
        const float4* xp = (const float4*)((const float*)Xv + (size_t)r * HID);
#pragma unroll
        for (int i = 0; i < 32; ++i) {
            const float4 v = xp[i];
            f16x2 a; a.x = (_Float16)v.x; a.y = (_Float16)v.y; xr[2 * i] = a;
            f16x2 b2; b2.x = (_Float16)v.z; b2.y = (_Float16)v.w; xr[2 * i + 1] = b2;
        }
    } else {
        const float4* xp = (const float4*)((const _Float16*)Xv + (size_t)r * HID);
#pragma unroll
        for (int i = 0; i < 16; ++i) {
            union { float4 f4; f16x2 p[4]; } u;
            u.f4 = xp[i];
#pragma unroll
            for (int q = 0; q < 4; ++q) xr[4 * i + q] = u.p[q];
        }
    }

    _Float16* orow = XW + (size_t)r * H3;

#pragma unroll 1
    for (int ub = 0; ub < 8; ++ub) {
        const int u0 = ub * 16;
        float az[16], ar[16], ah[16];
#pragma unroll
        for (int o = 0; o < 16; ++o) {
            az[o] = bias[u0 + o];
            ar[o] = bias[128 + u0 + o];
            ah[o] = bias[256 + u0 + o];
        }

#pragma unroll 2
        for (int k2 = 0; k2 < 64; ++k2) {
            const f16x2 x2 = xr[k2];
            const float4* wzv = (const float4*)(wpk + ((size_t)(0 * 64 + k2) << 7) + u0);
            const float4* wrv = (const float4*)(wpk + ((size_t)(1 * 64 + k2) << 7) + u0);
            const float4* whv = (const float4*)(wpk + ((size_t)(2 * 64 + k2) << 7) + u0);
#pragma unroll
            for (int g = 0; g < 4; ++g) {
                union { float4 f4; f16x2 p[4]; } u;
                u.f4 = wzv[g];
#pragma unroll
                for (int q = 0; q < 4; ++q) az[4 * g + q] = fdot2(x2, u.p[q], az[4 * g + q]);
            }
#pragma unroll
            for (int g = 0; g < 4; ++g) {
                union { float4 f4; f16x2 p[4]; } u;
                u.f4 = wrv[g];
#pragma unroll
                for (int q = 0; q < 4; ++q) ar[4 * g + q] = fdot2(x2, u.p[q], ar[4 * g + q]);
            }
#pragma unroll
            for (int g = 0; g < 4; ++g) {
                union { float4 f4; f16x2 p[4]; } u;
                u.f4 = whv[g];
#pragma unroll
                for (int q = 0; q < 4; ++q) ah[4 * g + q] = fdot2(x2, u.p[q], ah[4 * g + q]);
            }
        }

        union { f16x8 v8[2]; _Float16 e[16]; } pz, pr, ph;
#pragma unroll
        for (int o = 0; o < 16; ++o) {
            pz.e[o] = (_Float16)az[o];
            pr.e[o] = (_Float16)ar[o];
            ph.e[o] = (_Float16)ah[o];
        }
        f16x8* dz = (f16x8*)(orow + u0);
        f16x8* dr = (f16x8*)(orow + 128 + u0);
        f16x8* dh = (f16x8*)(orow + 256 + u0);
        dz[0] = pz.v8[0]; dz[1] = pz.v8[1];
        dr[0] = pr.v8[0]; dr[1] = pr.v8[1];
        dh[0] = ph.v8[0]; dh[1] = ph.v8[1];
    }
}

// ---------------------------------------------------------------------------
// gru_rec v3: one WG (512 thr, 8 waves) per batch. thread: j=t>>2 (unit),
// kh=t&3 (k-quarter of 32). 16-deep dot2 chains per gate; DPP quad reduce;
// gates redundant in all 4 kh lanes; h f16 double-buffer in LDS; xw prefetch
// ring depth 4, manual x4 unroll; one barrier/step.
// ---------------------------------------------------------------------------
__global__ __launch_bounds__(512, 1) void gru_rec(
    const _Float16* __restrict__ xw,   // [B*T, 384]  planes z|r|h
    const float*    __restrict__ rk,   // [128, 384]
    const float*    __restrict__ bias, // [2, 384], row 1 = recurrent bias
    _Float16*       __restrict__ h_out,// [B*T, 128] f16
    int T)
{
    const int b  = blockIdx.x;
    const int t  = threadIdx.x;
    const int j  = t >> 2;      // hidden unit 0..127
    const int kh = t & 3;       // k-quarter
    const int k0 = kh * 32;     // k base (32 values)

    __shared__ __align__(16) _Float16 hbuf[2][HID];

    // persistent weights: 3 gates x 16 f16x2 = 48 VGPRs
    f16x2 wz[16], wr[16], wh[16];
#pragma unroll
    for (int p = 0; p < 16; ++p) {
        const int k = k0 + 2 * p;
        const float* r0p = rk + (size_t)k * H3;
        const float* r1p = rk + (size_t)(k + 1) * H3;
        f16x2 a;
        a.x = (_Float16)r0p[j];       a.y = (_Float16)r1p[j];       wz[p] = a;
        a.x = (_Float16)r0p[j + 128]; a.y = (_Float16)r1p[j + 128]; wr[p] = a;
        a.x = (_Float16)r0p[j + 256]; a.y = (_Float16)r1p[j + 256]; wh[p] = a;
    }
    const float bz = bias[H3 + j];
    const float br = bias[H3 + 128 + j];
    const float bh = bias[H3 + 256 + j];

    if (t < HID) { hbuf[0][t] = (_Float16)0.f; hbuf[1][t] = (_Float16)0.f; }

    const _Float16* xwb = xw + (size_t)b * T * H3;
    _Float16*       hob = h_out + (size_t)b * T * HID;

    // prefetch ring depth 4 (slots a..d = steps 0..3)
    _Float16 az0, ar0, ah0, az1, ar1, ah1, az2, ar2, ah2, az3, ar3, ah3;
    {
        const _Float16* p0 = xwb;
        az0 = p0[j]; ar0 = p0[128 + j]; ah0 = p0[256 + j];
        const _Float16* p1 = xwb + H3;
        az1 = p1[j]; ar1 = p1[128 + j]; ah1 = p1[256 + j];
        const _Float16* p2 = xwb + 2 * H3;
        az2 = p2[j]; ar2 = p2[128 + j]; ah2 = p2[256 + j];
        const _Float16* p3 = xwb + 3 * H3;
        az3 = p3[j]; ar3 = p3[128 + j]; ah3 = p3[256 + j];
    }

    float h_old = 0.f;
    __syncthreads();

    auto STEP = [&](int step, int rbuf, _Float16& qz, _Float16& qr, _Float16& qh) {
        const f16x8* hp = (const f16x8*)(&hbuf[rbuf][k0]);
        float sz = 0.f, sr = 0.f, sh = 0.f;
#pragma unroll
        for (int i = 0; i < 4; ++i) {
            union { f16x8 v; f16x2 p[4]; } u;
            u.v = hp[i];
#pragma unroll
            for (int q = 0; q < 4; ++q) {
                sz = fdot2(u.p[q], wz[4 * i + q], sz);
                sr = fdot2(u.p[q], wr[4 * i + q], sr);
                sh = fdot2(u.p[q], wh[4 * i + q], sh);
            }
        }
        sz = quad_sum(sz); sr = quad_sum(sr); sh = quad_sum(sh);

        const float xz = (float)qz, xr = (float)qr, xh = (float)qh;
        if (step + 4 < T) {                       // reload this slot for step+4
            const _Float16* p = xwb + (size_t)(step + 4) * H3;
            qz = p[j]; qr = p[128 + j]; qh = p[256 + j];
        }

        const float z  = fsigmoid(xz + sz + bz);
        const float r  = fsigmoid(xr + sr + br);
        const float hh = ftanh_(xh + (sh + bh) * r);
        const float hn = z * h_old + (1.f - z) * hh;
        h_old = hn;

        if (kh == 0) {
            hbuf[rbuf ^ 1][j] = (_Float16)hn;
            hob[(size_t)step * HID + j] = (_Float16)hn;
        }
        __syncthreads();
    };

    for (int step = 0; step < T; step += 4) {
        STEP(step + 0, 0, az0, ar0, ah0);
        STEP(step + 1, 1, az1, ar1, ah1);
        STEP(step + 2, 0, az2, ar2, ah2);
        STEP(step + 3, 1, az3, ar3, ah3);
    }
}

// ---------------------------------------------------------------------------
// out_proj: out[r,:] = h_f16[r,:] @ wo + bo (fp32 out). Thread = row.
// ---------------------------------------------------------------------------
__global__ __launch_bounds__(256) void out_proj(
    const _Float16* __restrict__ Hf,  // [R,128] f16
    const float* __restrict__ wo,     // [128,5]
    const float* __restrict__ bo,     // [5]
    float*       __restrict__ out,    // [R,5]
    int R)
{
    const int r = blockIdx.x * 256 + threadIdx.x;
    if (r >= R) return;
    const f16x8* xp = (const f16x8*)(Hf + (size_t)r * HID);

    float a0 = bo[0], a1 = bo[1], a2 = bo[2], a3 = bo[3], a4 = bo[4];
#pragma unroll 4
    for (int c = 0; c < 16; ++c) {
        const f16x8 v = xp[c];
#pragma unroll
        for (int e = 0; e < 8; ++e) {
            const float xv = (float)v[e];
            const float* w = wo + (size_t)(8 * c + e) * OUTD;
            a0 = fmaf(xv, w[0], a0);
            a1 = fmaf(xv, w[1], a1);
            a2 = fmaf(xv, w[2], a2);
            a3 = fmaf(xv, w[3], a3);
            a4 = fmaf(xv, w[4], a4);
        }
    }
    float* op = out + (size_t)r * OUTD;
    op[0] = a0; op[1] = a1; op[2] = a2; op[3] = a3; op[4] = a4;
}

// ---------------------------------------------------------------------------
extern "C" void kernel_launch(void* const* d_in, const int* in_sizes, int n_in,
                              void* d_out, int out_size, void* d_ws, size_t ws_size,
                              hipStream_t stream) {
    const float* x   = (const float*)d_in[0];
    const float* k0  = (const float*)d_in[1];
    const float* rk0 = (const float*)d_in[2];
    const float* b0  = (const float*)d_in[3];
    const float* k1  = (const float*)d_in[4];
    const float* rk1 = (const float*)d_in[5];
    const float* b1  = (const float*)d_in[6];
    const float* k2  = (const float*)d_in[7];
    const float* rk2 = (const float*)d_in[8];
    const float* b2  = (const float*)d_in[9];
    const float* wo  = (const float*)d_in[10];
    const float* bo  = (const float*)d_in[11];
    float* out = (float*)d_out;

    const int BT = in_sizes[0] / HID;   // 64*2048 = 131072 rows
    const int T  = T_SEQ;               // 2048
    const int B  = BT / T;              // 64

    // ws layout: [xw f16 BT*384 = 100.6MB][h f16 BT*128 = 33.5MB][wpk 96KB]
    _Float16* xwbuf = (_Float16*)d_ws;
    _Float16* hbuf  = (_Float16*)((char*)d_ws + (size_t)BT * H3 * sizeof(_Float16));
    f16x2*    wpk   = (f16x2*)((char*)d_ws + (size_t)BT * H3 * sizeof(_Float16)
                                           + (size_t)BT * HID * sizeof(_Float16));

    const int pg = (BT + 255) / 256;
    const int wg = (3 * 64 * 128 + 255) / 256;

    pack_w         <<<wg, 256, 0, stream>>>(k0, wpk);
    in_proj<true>  <<<pg, 256, 0, stream>>>(x, wpk, b0, xwbuf, BT);
    gru_rec        <<<B, 512, 0, stream>>>(xwbuf, rk0, b0, hbuf, T);

    pack_w         <<<wg, 256, 0, stream>>>(k1, wpk);
    in_proj<false> <<<pg, 256, 0, stream>>>(hbuf, wpk, b1, xwbuf, BT);
    gru_rec        <<<B, 512, 0, stream>>>(xwbuf, rk1, b1, hbuf, T);

    pack_w         <<<wg, 256, 0, stream>>>(k2, wpk);
    in_proj<false> <<<pg, 256, 0, stream>>>(hbuf, wpk, b2, xwbuf, BT);
    gru_rec        <<<B, 512, 0, stream>>>(xwbuf, rk2, b2, hbuf, T);

    out_proj       <<<pg, 256, 0, stream>>>(hbuf, wo, bo, out, BT);
}

// Round 4
// 3453.962 us; speedup vs baseline: 2.2116x; 1.1161x over previous
//
#include <hip/hip_runtime.h>
#include <hip/hip_bf16.h>
#include <hip/hip_fp16.h>

// ---------------------------------------------------------------------------
// 3-layer GRU (Keras v2, reset_after=True), B=64 T=2048 F=H=128, OUT=5.
// Round 4:
//   gru_rec v4: KEY FIX — __syncthreads() emits s_waitcnt vmcnt(0) before
//     s_barrier, draining the xw prefetch every step (~800cy HBM latency
//     exposed per step; measured 1263 cy/step). Replaced with soft barrier
//     (s_waitcnt lgkmcnt(0); s_barrier) — LDS h handoff only needs lgkm;
//     xw loads are VGPR-private, guarded by compiler vmcnt(N) at use with
//     4-step slack >> HBM latency.
//   Also: z,r recurrent biases folded into in_proj bias; clamp-free
//     sigmoid/tanh (4/5 instr, NaN-safe); xw layout: z,r interleaved f16x2
//     plane + h plane -> 2 loads/step instead of 3.
// ---------------------------------------------------------------------------

#define HID   128
#define H3    384
#define OUTD  5
#define T_SEQ 2048

typedef _Float16 f16x2 __attribute__((ext_vector_type(2)));
typedef _Float16 f16x8 __attribute__((ext_vector_type(8)));

__device__ __forceinline__ float fdot2(f16x2 a, f16x2 b, float c) {
#if __has_builtin(__builtin_amdgcn_fdot2)
    return __builtin_amdgcn_fdot2(a, b, c, false);   // v_dot2_f32_f16
#else
    return fmaf((float)a.x, (float)b.x, fmaf((float)a.y, (float)b.y, c));
#endif
}

__device__ __forceinline__ float fexp2(float x) {
#if __has_builtin(__builtin_amdgcn_exp2f)
    return __builtin_amdgcn_exp2f(x);
#else
    return exp2f(x);
#endif
}

__device__ __forceinline__ float frcp(float x) {
#if __has_builtin(__builtin_amdgcn_rcpf)
    return __builtin_amdgcn_rcpf(x);
#else
    return 1.f / x;
#endif
}

// sigmoid(x) = 1/(1+exp(-x)); NaN-safe for all finite x (inf -> 0/1).
__device__ __forceinline__ float fsigmoid(float x) {
    return frcp(1.f + fexp2(x * -1.4426950408889634f));
}

// tanh(x) = 1 - 2/(1+exp(2x)); NaN-safe (x->-inf: exp->0 -> -1; +inf -> 1).
__device__ __forceinline__ float ftanh_(float x) {
    return fmaf(-2.f, frcp(1.f + fexp2(x * 2.8853900817779268f)), 1.f);
}

// barrier that does NOT drain vmcnt (unlike __syncthreads). LDS handoff only
// needs lgkmcnt(0); global prefetch loads stay in flight across steps.
__device__ __forceinline__ void soft_barrier() {
    asm volatile("s_waitcnt lgkmcnt(0)\n\ts_barrier" ::: "memory");
}

// butterfly sum over the kh quad (lanes xor 1, xor 2) on the VALU pipe
__device__ __forceinline__ float quad_sum(float x) {
#if __has_builtin(__builtin_amdgcn_mov_dpp)
    int i1 = __builtin_amdgcn_mov_dpp(__float_as_int(x), 0xB1, 0xF, 0xF, true); // [1,0,3,2]
    x += __int_as_float(i1);
    int i2 = __builtin_amdgcn_mov_dpp(__float_as_int(x), 0x4E, 0xF, 0xF, true); // [2,3,0,1]
    x += __int_as_float(i2);
#else
    x += __shfl_xor(x, 1);
    x += __shfl_xor(x, 2);
#endif
    return x;
}

// ---------------------------------------------------------------------------
// pack_w: Kw fp32 [128,384] -> wpk[g][k2][u] f16x2 = (Kw[2k2][g*128+u], Kw[2k2+1][g*128+u])
// ---------------------------------------------------------------------------
__global__ __launch_bounds__(256) void pack_w(const float* __restrict__ Kw,
                                              f16x2* __restrict__ wpk) {
    const int i = blockIdx.x * 256 + threadIdx.x;
    if (i >= 3 * 64 * 128) return;
    const int u  = i & 127;
    const int k2 = (i >> 7) & 63;
    const int g  = i >> 13;
    f16x2 v;
    v.x = (_Float16)Kw[(size_t)(2 * k2) * H3 + g * 128 + u];
    v.y = (_Float16)Kw[(size_t)(2 * k2 + 1) * H3 + g * 128 + u];
    wpk[i] = v;
}

// ---------------------------------------------------------------------------
// in_proj v4: XW row layout = [zr interleaved f16x2 x128 | h f16 x128].
// z,r planes get b_in + b_rec folded in; h plane b_in only.
// Thread = row; x row resident as f16x2; weights from wpk as float4 loads.
// ---------------------------------------------------------------------------
template<bool F32IN>
__global__ __launch_bounds__(256, 2) void in_proj(
    const void* __restrict__ Xv,     // [R,128] fp32 or f16
    const f16x2* __restrict__ wpk,   // [3][64][128]
    const float* __restrict__ bias,  // [2,384]: row0 input bias, row1 recurrent
    _Float16*   __restrict__ XW,     // [R,384] layout zr|h
    int R)
{
    const int r = blockIdx.x * 256 + threadIdx.x;
    if (r >= R) return;

    f16x2 xr[64];
    if (F32IN) {
        const float4* xp = (const float4*)((const float*)Xv + (size_t)r * HID);
#pragma unroll
        for (int i = 0; i < 32; ++i) {
            const float4 v = xp[i];
            f16x2 a; a.x = (_Float16)v.x; a.y = (_Float16)v.y; xr[2 * i] = a;
            f16x2 b2; b2.x = (_Float16)v.z; b2.y = (_Float16)v.w; xr[2 * i + 1] = b2;
        }
    } else {
        const float4* xp = (const float4*)((const _Float16*)Xv + (size_t)r * HID);
#pragma unroll
        for (int i = 0; i < 16; ++i) {
            union { float4 f4; f16x2 p[4]; } u;
            u.f4 = xp[i];
#pragma unroll
            for (int q = 0; q < 4; ++q) xr[4 * i + q] = u.p[q];
        }
    }

    _Float16* orow = XW + (size_t)r * H3;

#pragma unroll 1
    for (int ub = 0; ub < 8; ++ub) {
        const int u0 = ub * 16;
        float az[16], ar[16], ah[16];
#pragma unroll
        for (int o = 0; o < 16; ++o) {
            az[o] = bias[u0 + o]       + bias[384 + u0 + o];        // fold b_rec(z)
            ar[o] = bias[128 + u0 + o] + bias[384 + 128 + u0 + o];  // fold b_rec(r)
            ah[o] = bias[256 + u0 + o];                             // b_in only
        }

#pragma unroll 2
        for (int k2 = 0; k2 < 64; ++k2) {
            const f16x2 x2 = xr[k2];
            const float4* wzv = (const float4*)(wpk + ((size_t)(0 * 64 + k2) << 7) + u0);
            const float4* wrv = (const float4*)(wpk + ((size_t)(1 * 64 + k2) << 7) + u0);
            const float4* whv = (const float4*)(wpk + ((size_t)(2 * 64 + k2) << 7) + u0);
#pragma unroll
            for (int g = 0; g < 4; ++g) {
                union { float4 f4; f16x2 p[4]; } u;
                u.f4 = wzv[g];
#pragma unroll
                for (int q = 0; q < 4; ++q) az[4 * g + q] = fdot2(x2, u.p[q], az[4 * g + q]);
            }
#pragma unroll
            for (int g = 0; g < 4; ++g) {
                union { float4 f4; f16x2 p[4]; } u;
                u.f4 = wrv[g];
#pragma unroll
                for (int q = 0; q < 4; ++q) ar[4 * g + q] = fdot2(x2, u.p[q], ar[4 * g + q]);
            }
#pragma unroll
            for (int g = 0; g < 4; ++g) {
                union { float4 f4; f16x2 p[4]; } u;
                u.f4 = whv[g];
#pragma unroll
                for (int q = 0; q < 4; ++q) ah[4 * g + q] = fdot2(x2, u.p[q], ah[4 * g + q]);
            }
        }

        // store: zr interleaved pairs at 2*u0, h plane at 256+u0
        union { f16x8 v8[4]; f16x2 p2[16]; } zr;
        union { f16x8 v8[2]; _Float16 e[16]; } ph;
#pragma unroll
        for (int o = 0; o < 16; ++o) {
            f16x2 p; p.x = (_Float16)az[o]; p.y = (_Float16)ar[o];
            zr.p2[o] = p;
            ph.e[o] = (_Float16)ah[o];
        }
        f16x8* dzr = (f16x8*)(orow + 2 * u0);
#pragma unroll
        for (int g = 0; g < 4; ++g) dzr[g] = zr.v8[g];
        f16x8* dh = (f16x8*)(orow + 256 + u0);
        dh[0] = ph.v8[0]; dh[1] = ph.v8[1];
    }
}

// ---------------------------------------------------------------------------
// gru_rec v4: one WG (512 thr, 8 waves) per batch. thread: j=t>>2, kh=t&3.
// 16-deep dot2 chains per gate; DPP quad reduce; h f16 double-buffer in LDS;
// xw prefetch ring depth 4; SOFT barrier (lgkm-only) once per step.
// ---------------------------------------------------------------------------
__global__ __launch_bounds__(512, 1) void gru_rec(
    const _Float16* __restrict__ xw,   // [B*T, 384]  layout zr|h
    const float*    __restrict__ rk,   // [128, 384]
    const float*    __restrict__ bias, // [2, 384], row 1 = recurrent bias
    _Float16*       __restrict__ h_out,// [B*T, 128] f16
    int T)
{
    const int b  = blockIdx.x;
    const int t  = threadIdx.x;
    const int j  = t >> 2;      // hidden unit 0..127
    const int kh = t & 3;       // k-quarter
    const int k0 = kh * 32;     // k base (32 values)

    __shared__ __align__(16) _Float16 hbuf[2][HID];

    // persistent weights: 3 gates x 16 f16x2 = 48 VGPRs
    f16x2 wz[16], wr[16], wh[16];
#pragma unroll
    for (int p = 0; p < 16; ++p) {
        const int k = k0 + 2 * p;
        const float* r0p = rk + (size_t)k * H3;
        const float* r1p = rk + (size_t)(k + 1) * H3;
        f16x2 a;
        a.x = (_Float16)r0p[j];       a.y = (_Float16)r1p[j];       wz[p] = a;
        a.x = (_Float16)r0p[j + 128]; a.y = (_Float16)r1p[j + 128]; wr[p] = a;
        a.x = (_Float16)r0p[j + 256]; a.y = (_Float16)r1p[j + 256]; wh[p] = a;
    }
    const float bh = bias[H3 + 256 + j];   // only h-gate recurrent bias survives

    if (t < HID) { hbuf[0][t] = (_Float16)0.f; hbuf[1][t] = (_Float16)0.f; }

    const _Float16* xwb = xw + (size_t)b * T * H3;
    _Float16*       hob = h_out + (size_t)b * T * HID;

    // prefetch ring depth 4: per slot a packed (z,r) pair + h scalar
    f16x2 zr0, zr1, zr2, zr3;
    _Float16 xh0, xh1, xh2, xh3;
    {
        const _Float16* p0 = xwb;
        zr0 = *(const f16x2*)(p0 + 2 * j); xh0 = p0[256 + j];
        const _Float16* p1 = xwb + H3;
        zr1 = *(const f16x2*)(p1 + 2 * j); xh1 = p1[256 + j];
        const _Float16* p2 = xwb + 2 * H3;
        zr2 = *(const f16x2*)(p2 + 2 * j); xh2 = p2[256 + j];
        const _Float16* p3 = xwb + 3 * H3;
        zr3 = *(const f16x2*)(p3 + 2 * j); xh3 = p3[256 + j];
    }

    float h_old = 0.f;
    __syncthreads();

    auto STEP = [&](int step, int rbuf, f16x2& qzr, _Float16& qh) {
        const f16x8* hp = (const f16x8*)(&hbuf[rbuf][k0]);
        float sz = 0.f, sr = 0.f, sh = 0.f;
#pragma unroll
        for (int i = 0; i < 4; ++i) {
            union { f16x8 v; f16x2 p[4]; } u;
            u.v = hp[i];
#pragma unroll
            for (int q = 0; q < 4; ++q) {
                sz = fdot2(u.p[q], wz[4 * i + q], sz);
                sr = fdot2(u.p[q], wr[4 * i + q], sr);
                sh = fdot2(u.p[q], wh[4 * i + q], sh);
            }
        }
        sz = quad_sum(sz); sr = quad_sum(sr); sh = quad_sum(sh);

        const float xz = (float)qzr.x, xr = (float)qzr.y, xh = (float)qh;
        if (step + 4 < T) {                       // reload this slot for step+4
            const _Float16* p = xwb + (size_t)(step + 4) * H3;
            qzr = *(const f16x2*)(p + 2 * j); qh = p[256 + j];
        }

        const float z  = fsigmoid(xz + sz);
        const float r  = fsigmoid(xr + sr);
        const float hh = ftanh_(xh + (sh + bh) * r);
        const float hn = fmaf(z, h_old - hh, hh);
        h_old = hn;

        if (kh == 0) {
            hbuf[rbuf ^ 1][j] = (_Float16)hn;
            hob[(size_t)step * HID + j] = (_Float16)hn;
        }
        soft_barrier();   // lgkm-only: xw prefetch stays in flight
    };

    for (int step = 0; step < T; step += 4) {
        STEP(step + 0, 0, zr0, xh0);
        STEP(step + 1, 1, zr1, xh1);
        STEP(step + 2, 0, zr2, xh2);
        STEP(step + 3, 1, zr3, xh3);
    }
}

// ---------------------------------------------------------------------------
// out_proj: out[r,:] = h_f16[r,:] @ wo + bo (fp32 out). Thread = row.
// ---------------------------------------------------------------------------
__global__ __launch_bounds__(256) void out_proj(
    const _Float16* __restrict__ Hf,  // [R,128] f16
    const float* __restrict__ wo,     // [128,5]
    const float* __restrict__ bo,     // [5]
    float*       __restrict__ out,    // [R,5]
    int R)
{
    const int r = blockIdx.x * 256 + threadIdx.x;
    if (r >= R) return;
    const f16x8* xp = (const f16x8*)(Hf + (size_t)r * HID);

    float a0 = bo[0], a1 = bo[1], a2 = bo[2], a3 = bo[3], a4 = bo[4];
#pragma unroll 4
    for (int c = 0; c < 16; ++c) {
        const f16x8 v = xp[c];
#pragma unroll
        for (int e = 0; e < 8; ++e) {
            const float xv = (float)v[e];
            const float* w = wo + (size_t)(8 * c + e) * OUTD;
            a0 = fmaf(xv, w[0], a0);
            a1 = fmaf(xv, w[1], a1);
            a2 = fmaf(xv, w[2], a2);
            a3 = fmaf(xv, w[3], a3);
            a4 = fmaf(xv, w[4], a4);
        }
    }
    float* op = out + (size_t)r * OUTD;
    op[0] = a0; op[1] = a1; op[2] = a2; op[3] = a3; op[4] = a4;
}

// ---------------------------------------------------------------------------
extern "C" void kernel_launch(void* const* d_in, const int* in_sizes, int n_in,
                              void* d_out, int out_size, void* d_ws, size_t ws_size,
                              hipStream_t stream) {
    const float* x   = (const float*)d_in[0];
    const float* k0  = (const float*)d_in[1];
    const float* rk0 = (const float*)d_in[2];
    const float* b0  = (const float*)d_in[3];
    const float* k1  = (const float*)d_in[4];
    const float* rk1 = (const float*)d_in[5];
    const float* b1  = (const float*)d_in[6];
    const float* k2  = (const float*)d_in[7];
    const float* rk2 = (const float*)d_in[8];
    const float* b2  = (const float*)d_in[9];
    const float* wo  = (const float*)d_in[10];
    const float* bo  = (const float*)d_in[11];
    float* out = (float*)d_out;

    const int BT = in_sizes[0] / HID;   // 64*2048 = 131072 rows
    const int T  = T_SEQ;               // 2048
    const int B  = BT / T;              // 64

    // ws layout: [xw f16 BT*384 = 100.6MB][h f16 BT*128 = 33.5MB][wpk 96KB]
    _Float16* xwbuf = (_Float16*)d_ws;
    _Float16* hbuf  = (_Float16*)((char*)d_ws + (size_t)BT * H3 * sizeof(_Float16));
    f16x2*    wpk   = (f16x2*)((char*)d_ws + (size_t)BT * H3 * sizeof(_Float16)
                                           + (size_t)BT * HID * sizeof(_Float16));

    const int pg = (BT + 255) / 256;
    const int wg = (3 * 64 * 128 + 255) / 256;

    pack_w         <<<wg, 256, 0, stream>>>(k0, wpk);
    in_proj<true>  <<<pg, 256, 0, stream>>>(x, wpk, b0, xwbuf, BT);
    gru_rec        <<<B, 512, 0, stream>>>(xwbuf, rk0, b0, hbuf, T);

    pack_w         <<<wg, 256, 0, stream>>>(k1, wpk);
    in_proj<false> <<<pg, 256, 0, stream>>>(hbuf, wpk, b1, xwbuf, BT);
    gru_rec        <<<B, 512, 0, stream>>>(xwbuf, rk1, b1, hbuf, T);

    pack_w         <<<wg, 256, 0, stream>>>(k2, wpk);
    in_proj<false> <<<pg, 256, 0, stream>>>(hbuf, wpk, b2, xwbuf, BT);
    gru_rec        <<<B, 512, 0, stream>>>(xwbuf, rk2, b2, hbuf, T);

    out_proj       <<<pg, 256, 0, stream>>>(hbuf, wo, bo, out, BT);
}